// Round 1
// baseline (260.630 us; speedup 1.0000x reference)
//
#include <hip/hip_runtime.h>

#define SQRT5F 2.2360679774997896f

// out[i,a,j,b] = c^2 * ( (a==b) * A(i,j) * inv_l2[a]  -  5*fr(i,j)*D[i,j,a]*D[i,j,b] )
// with D[i,j,k] = (X1[i,k]-X2[j,k]) * inv_l2[k]
//      r^2      = sum_k (X1[i,k]-X2[j,k])^2 * inv_l2[k]
//      fr       = (5/3) * exp(-sqrt5 * r)
//      A        = fr * (1 + sqrt5 * r)
//
// d is hardcoded to 8 (problem shape). One thread per (i,j); each thread
// writes 64 floats (16x float4). For fixed a, lane j stores 32B at
// i*65536 + a*8192 + j*8 -> a wave64 covers a contiguous 2KiB run: coalesced.

__global__ __launch_bounds__(256) void deriv2_matern52_kernel(
    const float* __restrict__ X1,
    const float* __restrict__ X2,
    const float* __restrict__ c_ptr,
    const float* __restrict__ l_ptr,
    float* __restrict__ out,
    int m /* = 1024 */)
{
    const int jblocks = m >> 8;                 // blocks of 256 j per i
    const int i  = blockIdx.x / jblocks;
    const int jb = blockIdx.x - i * jblocks;
    const int j  = (jb << 8) + threadIdx.x;

    const float c  = c_ptr[0];
    const float c2 = c * c;

    // lengthscales -> 1/l^2 (wave-uniform; compiler keeps these scalar)
    float inv_l2[8];
#pragma unroll
    for (int k = 0; k < 8; ++k) {
        const float lv = l_ptr[k];
        inv_l2[k] = 1.0f / (lv * lv);
    }

    // rows (32B each, aligned)
    const float4 x1a = ((const float4*)(X1 + (size_t)i * 8))[0];
    const float4 x1b = ((const float4*)(X1 + (size_t)i * 8))[1];
    const float4 x2a = ((const float4*)(X2 + (size_t)j * 8))[0];
    const float4 x2b = ((const float4*)(X2 + (size_t)j * 8))[1];

    float dx[8] = { x1a.x - x2a.x, x1a.y - x2a.y, x1a.z - x2a.z, x1a.w - x2a.w,
                    x1b.x - x2b.x, x1b.y - x2b.y, x1b.z - x2b.z, x1b.w - x2b.w };

    float D[8];
    float r2 = 0.0f;
#pragma unroll
    for (int k = 0; k < 8; ++k) {
        D[k] = dx[k] * inv_l2[k];
        r2 += dx[k] * D[k];              // dx^2 * inv_l2
    }

    const float r  = sqrtf(r2);
    const float fr = (5.0f / 3.0f) * expf(-SQRT5F * r);
    const float A  = fr * (1.0f + SQRT5F * r);

    const float Ac  = A * c2;            // diagonal coefficient
    const float cf  = -5.0f * fr * c2;   // off-diag/pair coefficient

    float Dc[8];
#pragma unroll
    for (int k = 0; k < 8; ++k) Dc[k] = cf * D[k];

    // out base for (i, a=0, j, b=0): i*d*m*d + j*d
    float* op = out + (size_t)i * (size_t)(8 * m * 8) + (size_t)j * 8;
    const size_t astride = (size_t)m * 8;   // stride between consecutive a

#pragma unroll
    for (int a = 0; a < 8; ++a) {
        float v[8];
#pragma unroll
        for (int b = 0; b < 8; ++b) v[b] = Dc[a] * D[b];
        v[a] += Ac * inv_l2[a];

        float4* dst = (float4*)(op + (size_t)a * astride);
        dst[0] = make_float4(v[0], v[1], v[2], v[3]);
        dst[1] = make_float4(v[4], v[5], v[6], v[7]);
    }
}

extern "C" void kernel_launch(void* const* d_in, const int* in_sizes, int n_in,
                              void* d_out, int out_size, void* d_ws, size_t ws_size,
                              hipStream_t stream) {
    const float* X1 = (const float*)d_in[0];
    const float* X2 = (const float*)d_in[1];
    const float* c  = (const float*)d_in[2];
    const float* l  = (const float*)d_in[3];
    float* out = (float*)d_out;

    const int d = in_sizes[3];        // 8
    const int n = in_sizes[0] / d;    // 1024
    const int m = in_sizes[1] / d;    // 1024

    const int jblocks = m >> 8;       // 256 j per block
    dim3 grid(n * jblocks);
    dim3 block(256);
    deriv2_matern52_kernel<<<grid, block, 0, stream>>>(X1, X2, c, l, out, m);
}

// Round 2
// 256.583 us; speedup vs baseline: 1.0158x; 1.0158x over previous
//
#include <hip/hip_runtime.h>

#define SQRT5F 2.2360679774997896f

// out[i,a,j,b] = c^2 * ( (a==b) * A(i,j) * inv_l2[a]  -  5*fr(i,j)*D[i,j,a]*D[i,j,b] )
// with D[i,j,k] = (X1[i,k]-X2[j,k]) * inv_l2[k]
//      r^2      = sum_k (X1[i,k]-X2[j,k])^2 * inv_l2[k]
//      fr       = (5/3) * exp(-sqrt5 * r)
//      A        = fr * (1 + sqrt5 * r)
//
// d hardcoded to 8. TWO threads per (i,j) pair: t>>1 = j-within-block,
// t&1 = which half (4 floats) of each b-run this thread stores.
// Lane t stores at byte offset t*16 within the per-a run -> every
// global_store_dwordx4 is 64 lanes x contiguous 16B = dense 1 KiB.
// (Previous version had lanes at 32B stride per instruction -> 1.0 TB/s.)

__global__ __launch_bounds__(256) void deriv2_matern52_kernel(
    const float* __restrict__ X1,
    const float* __restrict__ X2,
    const float* __restrict__ c_ptr,
    const float* __restrict__ l_ptr,
    float* __restrict__ out,
    int m /* = 1024 */)
{
    const int t = threadIdx.x;
    const int jblocks = m >> 7;                 // 128 pairs per block
    const int i  = blockIdx.x / jblocks;
    const int jb = blockIdx.x - i * jblocks;
    const int j  = (jb << 7) + (t >> 1);
    const int h  = t & 1;                       // half of the 8-float b-run
    const int b0 = h << 2;                      // 0 or 4

    const float c  = c_ptr[0];
    const float c2 = c * c;

    // lengthscales -> 1/l^2 (wave-uniform; scalar-cached)
    float inv_l2[8];
#pragma unroll
    for (int k = 0; k < 8; ++k) {
        const float lv = l_ptr[k];
        inv_l2[k] = 1.0f / (lv * lv);
    }

    // rows (32B each, aligned)
    const float4 x1a = ((const float4*)(X1 + (size_t)i * 8))[0];
    const float4 x1b = ((const float4*)(X1 + (size_t)i * 8))[1];
    const float4 x2a = ((const float4*)(X2 + (size_t)j * 8))[0];
    const float4 x2b = ((const float4*)(X2 + (size_t)j * 8))[1];

    const float dx[8] = { x1a.x - x2a.x, x1a.y - x2a.y, x1a.z - x2a.z, x1a.w - x2a.w,
                          x1b.x - x2b.x, x1b.y - x2b.y, x1b.z - x2b.z, x1b.w - x2b.w };

    float D[8];
    float r2 = 0.0f;
#pragma unroll
    for (int k = 0; k < 8; ++k) {
        D[k] = dx[k] * inv_l2[k];
        r2 += dx[k] * D[k];              // dx^2 * inv_l2
    }

    const float r  = sqrtf(r2);
    const float fr = (5.0f / 3.0f) * expf(-SQRT5F * r);
    const float A  = fr * (1.0f + SQRT5F * r);

    const float Ac = A * c2;             // diagonal coefficient
    const float cf = -5.0f * fr * c2;    // pair coefficient

    // this thread's 4 b-values, pre-scaled
    const float Db[4] = { D[b0 + 0], D[b0 + 1], D[b0 + 2], D[b0 + 3] };

    // out base for (i, a=0, j, b=b0): i*d*m*d + j*d + b0
    float* op = out + (size_t)i * (size_t)(8 * m * 8) + (size_t)j * 8 + b0;
    const size_t astride = (size_t)m * 8;    // stride between consecutive a

#pragma unroll
    for (int a = 0; a < 8; ++a) {
        const float Dca = cf * D[a];
        float v[4];
#pragma unroll
        for (int k = 0; k < 4; ++k) v[k] = Dca * Db[k];
        const int da = a - b0;
        if (da >= 0 && da < 4) v[da] += Ac * inv_l2[a];   // compile-time resolved

        *(float4*)(op + (size_t)a * astride) = make_float4(v[0], v[1], v[2], v[3]);
    }
}

extern "C" void kernel_launch(void* const* d_in, const int* in_sizes, int n_in,
                              void* d_out, int out_size, void* d_ws, size_t ws_size,
                              hipStream_t stream) {
    const float* X1 = (const float*)d_in[0];
    const float* X2 = (const float*)d_in[1];
    const float* c  = (const float*)d_in[2];
    const float* l  = (const float*)d_in[3];
    float* out = (float*)d_out;

    const int d = in_sizes[3];        // 8
    const int n = in_sizes[0] / d;    // 1024
    const int m = in_sizes[1] / d;    // 1024

    const int jblocks = m >> 7;       // 128 pairs (256 threads) per block
    dim3 grid(n * jblocks);
    dim3 block(256);
    deriv2_matern52_kernel<<<grid, block, 0, stream>>>(X1, X2, c, l, out, m);
}